// Round 13
// baseline (139.199 us; speedup 1.0000x reference)
//
#include <hip/hip_runtime.h>

// CRF log-likelihood: B=32, T=512, L=64.
// out = sum_b( -path_score[b] + log_Z[b] )
//
// ROUND-13 MEASUREMENT PROBE (correct output, deliberately repeated scan):
// r5/r10/r12 all land at ~22 us despite major inner-loop changes, so the
// cost decomposition is unknown. This kernel wraps ONLY the scan+epilogue
// in a REP=16 x #pragma unroll 1 loop (staging/E-setup/path-score hoist
// out as loop invariants). Each rep is kept live and non-CSE-able via
// empty asm; every rep computes the identical contrib, so the output is
// bit-identical to r12. dur = intercept + 15*S decomposes exec:
//   S = pure scan cost, intercept = staging + latency + launch floor.
// Side effect: chunk kernel now outlasts the 40us poison-fills -> we get
// its VGPR_Count / VALUBusy / FETCH_SIZE in the top-5 counter rows.

#define CRF_B 32
#define CRF_T 512
#define CRF_L 64
#define NCHUNK 64
#define CHUNK 8               // CRF_T / NCHUNK
#define BURN 8
#define NSTEP (BURN + CHUNK)  // 16
#define NTASK (CRF_B * NCHUNK)   // 2048
#define WPB 4                 // independent waves per block
#define NBLK (NTASK / WPB)    // 512
#define REP 16                // scan repetitions (measurement)
#define LN2F 0.69314718055994530942f

__device__ __forceinline__ float wave_sum(float v) {
#pragma unroll
    for (int off = 32; off; off >>= 1) v += __shfl_xor(v, off);
    return v;
}

// one matvec step: y_j = (sum_i w_i * E_ij) * eh
// readlane -> SGPR broadcast; v_fmac_f32 with SGPR src0 + VGPR src1.
__device__ __forceinline__ float matvec_step(float wn, const float* E, float eh) {
    float acc[8] = {0.f, 0.f, 0.f, 0.f, 0.f, 0.f, 0.f, 0.f};
    const int wb = __float_as_int(wn);
#pragma unroll
    for (int grp = 0; grp < 8; ++grp) {
        int w[8];
#pragma unroll
        for (int k = 0; k < 8; ++k)
            w[k] = __builtin_amdgcn_readlane(wb, grp * 8 + k);
#pragma unroll
        for (int k = 0; k < 8; ++k)
            asm("v_fmac_f32 %0, %1, %2"
                : "+v"(acc[k])
                : "s"(w[k]), "v"(E[grp * 8 + k]));
    }
    float y = (((acc[0] + acc[1]) + (acc[2] + acc[3])) +
               ((acc[4] + acc[5]) + (acc[6] + acc[7])));
    return y * eh;
}

__device__ __forceinline__ float pow2_renorm(float wn) {  // exact, scale discarded
    unsigned w0 = (unsigned)__builtin_amdgcn_readfirstlane(
        (int)__float_as_uint(wn));
    int ex = (int)((w0 >> 23) & 0xffu) - 127;
    return ldexpf(wn, -ex);
}

__global__ __launch_bounds__(256, 1)
void crf_chunk_kernel(const float* __restrict__ inputs,
                      const float* __restrict__ labels,
                      const float* __restrict__ trans,
                      float* __restrict__ partial) {
    const int wid  = threadIdx.x >> 6;
    const int j    = threadIdx.x & 63;
    const int task = blockIdx.x * WPB + wid;  // 0..NTASK-1
    const int b = task >> 6;                  // / NCHUNK
    const int c = task & (NCHUNK - 1);

    const int r0     = c * CHUNK;
    const int base_h = (c == 0) ? 0 : (r0 - BURN);   // >= 0 (BURN == CHUNK)
    const int base_r = (c == 0) ? 0 : (r0 - 1);

    const float* inb = inputs + (size_t)b * CRF_T * CRF_L + j;
    const float* lab = labels + (size_t)b * CRF_T * CRF_L + j;

    // ---- staging (loop-invariant; hoisted out of the rep loop) ----
    float H[NSTEP];
#pragma unroll
    for (int s = 0; s < NSTEP; ++s) H[s] = inb[(base_h + s) * CRF_L];
    float R[CHUNK + 1];
#pragma unroll
    for (int s = 0; s <= CHUNK; ++s) R[s] = lab[(base_r + s) * CRF_L];

    float E[CRF_L];
#pragma unroll
    for (int i = 0; i < CRF_L; ++i) {
        E[i] = __expf(trans[i * CRF_L + j]);
        asm volatile("" : "+v"(E[i]));
    }

    float EH[NSTEP];
#pragma unroll
    for (int s = 0; s < NSTEP; ++s) EH[s] = __expf(H[s]);

    // ---- path score (loop-invariant) ----
    float hs = 0.0f, gv = 0.0f;
    if (c == 0) {
#pragma unroll
        for (int s = 0; s < CHUNK; ++s) hs = fmaf(H[s], R[s], hs);
        int vprev = 0, vcur = 0;
#pragma unroll
        for (int s = 0; s < CHUNK; ++s) {
            int idx = __ffsll(__ballot(R[s] > 0.5f)) - 1;  // wave-uniform
            if (s < CHUNK - 1) vprev = (j == s) ? idx : vprev;
            if (s > 0)         vcur  = (j == s - 1) ? idx : vcur;
        }
        if (j < CHUNK - 1) gv = trans[vprev * CRF_L + vcur];
    } else {
#pragma unroll
        for (int s = 0; s < CHUNK; ++s) hs = fmaf(H[BURN + s], R[1 + s], hs);
        int vprev = 0, vcur = 0;
#pragma unroll
        for (int s = 0; s <= CHUNK; ++s) {
            int idx = __ffsll(__ballot(R[s] > 0.5f)) - 1;  // wave-uniform
            if (s < CHUNK) vprev = (j == s) ? idx : vprev;
            if (s > 0)     vcur  = (j == s - 1) ? idx : vcur;
        }
        if (j < CHUNK) gv = trans[vprev * CRF_L + vcur];
    }
    const float path = wave_sum(hs + gv);

    // ---- measured region: REP identical scans (output = last rep) ----
    float contrib = 0.0f;
#pragma unroll 1
    for (int rep = 0; rep < REP; ++rep) {
        asm volatile("" : "+v"(EH[0]));       // defeat CSE across reps
        float wn, base2;
        if (c == 0) {
            wn = EH[0];
            base2 = 0.0f;
#pragma unroll
            for (int s = 1; s < CHUNK; ++s) wn = matvec_step(wn, E, EH[s]);
        } else {
            wn = 1.0f;
#pragma unroll
            for (int s = 0; s < BURN; ++s) {
                wn = matvec_step(wn, E, EH[s]);
                if (s == 3) wn = pow2_renorm(wn);
            }
            wn = pow2_renorm(wn);             // common frame for base2 & end
            base2 = __log2f(wave_sum(wn));
#pragma unroll
            for (int s = 0; s < CHUNK; ++s) wn = matvec_step(wn, E, EH[BURN + s]);
        }
        float ssum = wave_sum(wn);
        contrib = (__log2f(ssum) - base2) * LN2F - path;
        asm volatile("" :: "v"(contrib));     // keep every rep live (no DCE)
    }

    if (j == 0) partial[task] = contrib;
}

__global__ __launch_bounds__(1024)
void crf_reduce_kernel(const float* __restrict__ partial, float* __restrict__ out) {
    const int tid = threadIdx.x;
    __shared__ float s[16];
    float v = partial[tid] + partial[tid + 1024];
    v = wave_sum(v);
    if ((tid & 63) == 0) s[tid >> 6] = v;
    __syncthreads();
    if (tid < 64) {
        float u = (tid < 16) ? s[tid] : 0.0f;
        u = wave_sum(u);
        if (tid == 0) out[0] = u;
    }
}

extern "C" void kernel_launch(void* const* d_in, const int* in_sizes, int n_in,
                              void* d_out, int out_size, void* d_ws, size_t ws_size,
                              hipStream_t stream) {
    const float* inputs = (const float*)d_in[0];
    const float* labels = (const float*)d_in[1];
    const float* trans  = (const float*)d_in[2];
    float* out = (float*)d_out;
    float* partial = (float*)d_ws;  // NTASK floats = 8 KB

    crf_chunk_kernel<<<NBLK, 256, 0, stream>>>(inputs, labels, trans, partial);
    crf_reduce_kernel<<<1, 1024, 0, stream>>>(partial, out);
}